// Round 13
// baseline (53.879 us; speedup 1.0000x reference)
//
#include <hip/hip_runtime.h>

#define B_    4
#define CIN_  64
#define H_    128
#define W_    128
#define COUT_ 64
#define HW    (H_*W_)
#define KPOS  576

typedef __attribute__((ext_vector_type(8))) short    bf16x8;
typedef __attribute__((ext_vector_type(4))) short    bf16x4;
typedef __attribute__((ext_vector_type(4))) float    f32x4;
typedef __attribute__((ext_vector_type(4))) _Float16 f16x4;
typedef __attribute__((ext_vector_type(8))) _Float16 f16x8;

static __device__ __forceinline__ unsigned short f2bf(float f) {
    union { float f; unsigned u; } a; a.f = f;
    unsigned r = a.u + 0x7fffu + ((a.u >> 16) & 1u);   // RNE
    return (unsigned short)(r >> 16);
}
static __device__ __forceinline__ float bfl(unsigned u) {
    union { unsigned x; float f; } a; a.x = u << 16; return a.f;
}

// Barrier that waits ONLY on LDS ops (lgkmcnt), never vmcnt.
static __device__ __forceinline__ void softbar() {
    asm volatile("s_waitcnt lgkmcnt(0)\n\ts_barrier" ::: "memory");
}

#define XT_HALFS   4194304                       // B*HW*64 NHWC f16 image
#define WP_HALFS   36864                         // wt[k][co][c] f16
#define META_CNT   (B_*9*HW)                     // 589824
#define OFFS_BYTE  ((XT_HALFS + WP_HALFS) * 2)            // 8462336
#define WTS_BYTE   (OFFS_BYTE + META_CNT * 4)             // 10821632
#define WS_NEED3   ((size_t)(WTS_BYTE + META_CNT * 8))    // ~15.5 MB

// ================= fused prep: xpose | meta | weight (all f16) =============
__global__ __launch_bounds__(256)
void prep_all(const float* __restrict__ x,
              const float* __restrict__ offset,
              const float* __restrict__ mask,
              const float* __restrict__ w,
              _Float16* __restrict__ xT,
              _Float16* __restrict__ wt,
              unsigned* __restrict__ mOffs,
              f16x4* __restrict__ mWts)
{
    const int bid = blockIdx.x;
    const int t   = threadIdx.x;

    if (bid < 512) {
        // ---- x NCHW f32 -> NHWC f16 (one (b,y) row per block) ----
        __shared__ _Float16 ld[64 * 132];
        const int b = bid >> 7;
        const int y = bid & 127;
        const float* src = x + (size_t)b * 64 * HW + y * W_;
        #pragma unroll
        for (int i = 0; i < 8; ++i) {
            const int e4 = (t + i * 256) * 4;
            const int c  = e4 >> 7;
            const int x0 = e4 & 127;
            const float4 v = *(const float4*)(src + (size_t)c * HW + x0);
            _Float16* d = &ld[c * 132 + x0];
            d[0] = (_Float16)v.x; d[1] = (_Float16)v.y;
            d[2] = (_Float16)v.z; d[3] = (_Float16)v.w;
        }
        __syncthreads();
        _Float16* dst = xT + ((size_t)b * HW + (size_t)y * W_) * 64;
        #pragma unroll
        for (int i = 0; i < 4; ++i) {
            const int o    = (t + i * 256) * 8;
            const int xcol = o >> 6;
            const int c0   = o & 63;
            union { f16x8 v; _Float16 u[8]; } pk;
            #pragma unroll
            for (int j = 0; j < 8; ++j) pk.u[j] = ld[(c0 + j) * 132 + xcol];
            *(f16x8*)(dst + o) = pk.v;
        }
    } else if (bid < 2816) {
        // ---- sampling metadata per (b,tap,pixel) ----
        const int i  = (bid - 512) * 256 + t;
        const int gp = i & (HW - 1);
        const int bk = i >> 14;              // b*9 + k
        const int b  = bk / 9;
        const int k  = bk - b * 9;
        const int ho = gp >> 7, wo = gp & 127;
        const float dy = offset[(size_t)(b * 18 + 2 * k) * HW + gp];
        const float dx = offset[(size_t)(b * 18 + 2 * k + 1) * HW + gp];
        const float mm = mask[(size_t)bk * HW + gp];
        const float py  = dy + (float)(k / 3) + (float)(ho - 1);   // PAD=1
        const float pxx = dx + (float)(k % 3) + (float)(wo - 1);
        const float y0f = floorf(py), x0f = floorf(pxx);
        const float wy = py - y0f, wx = pxx - x0f;
        const int y0 = (int)y0f, x0 = (int)x0f;
        const int y1 = y0 + 1,  x1 = x0 + 1;
        const bool vy0 = (y0 >= 0) & (y0 < H_), vy1 = (y1 >= 0) & (y1 < H_);
        const bool vx0 = (x0 >= 0) & (x0 < W_), vx1 = (x1 >= 0) & (x1 < W_);
        const int cy0 = min(max(y0, 0), H_-1), cy1 = min(max(y1, 0), H_-1);
        const int cx0 = min(max(x0, 0), W_-1), cx1 = min(max(x1, 0), W_-1);
        mOffs[i] = (unsigned)cy0 | ((unsigned)cy1 << 8)
                 | ((unsigned)cx0 << 16) | ((unsigned)cx1 << 24);
        f16x4 wv;
        wv[0] = (_Float16)((vy0 && vx0) ? (1.f - wy) * (1.f - wx) * mm : 0.f);
        wv[1] = (_Float16)((vy0 && vx1) ? (1.f - wy) * wx * mm         : 0.f);
        wv[2] = (_Float16)((vy1 && vx0) ? wy * (1.f - wx) * mm         : 0.f);
        wv[3] = (_Float16)((vy1 && vx1) ? wy * wx * mm                 : 0.f);
        mWts[i] = wv;
    } else {
        // ---- weight -> f16, tap-major: wt[k][co][c] ----
        const int i = (bid - 2816) * 256 + t;
        if (i < 9 * 64 * 64) {
            const int k  = i >> 12;
            const int r  = i & 4095;
            const int co = r >> 6;
            const int c  = r & 63;
            wt[i] = (_Float16)w[co * KPOS + c * 9 + k];
        }
    }
}

// ================= main: A-fragment in registers (no vP), Wk LDS dbuf ======
// Gather wave layout pxl = lane&15, oct = lane>>4: the bilinear combine
// output per lane IS the MFMA A-fragment (row = lane&15, k = oct*8 + pass*32).
// LDS halved to Wk only; 2-tap-deep gather prefetch; lgkm-only barrier.
// Loop: wkload(k+1) | combine(k) | metald(k+2) | domfma(k) | gather(k+2)
//       | finishW(k+1) | softbar.
__global__ __launch_bounds__(256, 4)
void dcn_f16(const _Float16* __restrict__ xT,
             const unsigned* __restrict__ mOffs,
             const f16x4* __restrict__ mWts,
             const float* __restrict__ bias,
             const _Float16* __restrict__ wprep,
             float* __restrict__ out)
{
    __shared__ _Float16 Wk[2][64][72];

    const int t   = threadIdx.x;
    const int bid = blockIdx.x;
    const int wk  = ((bid & 7) << 7) | (bid >> 3);   // XCD-chunked swizzle
    const int xh  = wk & 1;
    const int ho  = (wk >> 1) & 127;
    const int b   = wk >> 8;
    const int cq  = t >> 6;
    const int lane = t & 63;
    const int pxl  = lane & 15;          // pixel = MFMA A/D row
    const int oct  = lane >> 4;          // k-frag oct (0..3)
    const int cho  = oct * 8;            // channel offset of this lane's slice

    f32x4 acc[4];
    #pragma unroll
    for (int i = 0; i < 4; ++i) acc[i] = (f32x4){0.f, 0.f, 0.f, 0.f};

    const _Float16* xTb = xT + (size_t)b * HW * 64;
    const int gp    = ho * W_ + xh * 64 + cq * 16 + pxl;
    const int mbase = (b * 9) << 14;

    // rolling pipeline state (static indices under full unroll)
    unsigned mO[2]; f16x4 mW[2];
    f16x8 cr[2][2][4];                   // [tap parity][pass][corner]
    f16x8 wa0, wa1;                      // W-stage registers

    auto metald = [&](int k, int s) {
        const int mi = mbase + (k << 14) + gp;
        mO[s] = mOffs[mi];
        mW[s] = mWts[mi];
    };
    auto gather = [&](int k, int s) {
        const unsigned pk = mO[s];
        const int y0c = pk & 255,         y1c = (pk >> 8) & 255;
        const int x0c = (pk >> 16) & 255, x1c = (int)(pk >> 24);
        const int p00 = (((y0c << 7) | x0c) << 6) + cho;
        const int p01 = (((y0c << 7) | x1c) << 6) + cho;
        const int p10 = (((y1c << 7) | x0c) << 6) + cho;
        const int p11 = (((y1c << 7) | x1c) << 6) + cho;
        #pragma unroll
        for (int pass = 0; pass < 2; ++pass) {
            const int o = pass * 32;
            cr[s][pass][0] = *(const f16x8*)(xTb + p00 + o);
            cr[s][pass][1] = *(const f16x8*)(xTb + p01 + o);
            cr[s][pass][2] = *(const f16x8*)(xTb + p10 + o);
            cr[s][pass][3] = *(const f16x8*)(xTb + p11 + o);
        }
    };
    auto wkload = [&](int k) {
        const int j = t * 8;
        wa0 = *(const f16x8*)(wprep + k * 4096 + j);
        wa1 = *(const f16x8*)(wprep + k * 4096 + 2048 + j);
    };
    auto finishW = [&](int s) {
        const int j  = t * 8;
        *(f16x8*)&Wk[s][j >> 6][j & 63] = wa0;
        const int j2 = 2048 + j;
        *(f16x8*)&Wk[s][j2 >> 6][j2 & 63] = wa1;
    };
    auto combine = [&](int s, f16x8& a0, f16x8& a1) {
        const _Float16 w0 = mW[s][0];
        const _Float16 w1 = mW[s][1];
        const _Float16 w2 = mW[s][2];
        const _Float16 w3 = mW[s][3];
        a0 = cr[s][0][0] * w0 + cr[s][0][1] * w1
           + cr[s][0][2] * w2 + cr[s][0][3] * w3;
        a1 = cr[s][1][0] * w0 + cr[s][1][1] * w1
           + cr[s][1][2] * w2 + cr[s][1][3] * w3;
    };
    auto domfma = [&](int k, const f16x8& a0, const f16x8& a1) {
        const int s  = k & 1;
        const int kc = oct * 8;
        #pragma unroll
        for (int nt = 0; nt < 4; ++nt) {
            const f16x8 b0 = *(const f16x8*)&Wk[s][nt * 16 + pxl][kc];
            acc[nt] = __builtin_amdgcn_mfma_f32_16x16x32_f16(a0, b0, acc[nt], 0, 0, 0);
        }
        #pragma unroll
        for (int nt = 0; nt < 4; ++nt) {
            const f16x8 b1 = *(const f16x8*)&Wk[s][nt * 16 + pxl][32 + kc];
            acc[nt] = __builtin_amdgcn_mfma_f32_16x16x32_f16(a1, b1, acc[nt], 0, 0, 0);
        }
    };

    // ---- prologue: taps 0,1 gathers in flight; Wk[0] staged ----
    metald(0, 0);
    metald(1, 1);
    gather(0, 0);
    gather(1, 1);
    wkload(0);
    finishW(0);
    softbar();

    #pragma unroll
    for (int k = 0; k < 9; ++k) {
        const int s = k & 1;
        if (k < 8) wkload(k + 1);        // next tap's W into regs (L1-hot)
        f16x8 a0, a1;
        combine(s, a0, a1);              // consume cr[s]/mW[s] -> A-frags
        if (k < 7) metald(k + 2, s);     // slot s now free
        domfma(k, a0, a1);               // covers meta-load latency
        if (k < 7) gather(k + 2, s);     // issue 2 taps ahead
        if (k < 8) {
            finishW(s ^ 1);              // Wk[s^1] <- tap k+1 weights
            softbar();                   // lgkm-only; gathers stay in flight
        }
    }

    // ---- epilogue: D col = lane&15 (co), row = oct*4+j (pixel) ----
    const int px0 = cq * 16 + oct * 4;
    #pragma unroll
    for (int nt = 0; nt < 4; ++nt) {
        const int co = nt * 16 + pxl;
        const float bb = bias[co];
        float4 r;
        r.x = acc[nt][0] + bb;
        r.y = acc[nt][1] + bb;
        r.z = acc[nt][2] + bb;
        r.w = acc[nt][3] + bb;
        *(float4*)&out[(((size_t)b * COUT_ + co) * H_ + ho) * W_ + xh * 64 + px0] = r;
    }
}

// ================= fallback path (ws too small): R4 bf16 kernels ===========
__global__ __launch_bounds__(256)
void xpose_bf16(const float* __restrict__ x, unsigned short* __restrict__ xT)
{
    __shared__ unsigned short ld[64 * 132];
    const int t   = threadIdx.x;
    const int blk = blockIdx.x;
    const int b   = blk >> 7;
    const int y   = blk & 127;
    const float* src = x + (size_t)b * 64 * HW + y * W_;
    #pragma unroll
    for (int i = 0; i < 8; ++i) {
        const int e4 = (t + i * 256) * 4;
        const int c  = e4 >> 7;
        const int x0 = e4 & 127;
        const float4 v = *(const float4*)(src + (size_t)c * HW + x0);
        unsigned short* d = &ld[c * 132 + x0];
        d[0] = f2bf(v.x); d[1] = f2bf(v.y); d[2] = f2bf(v.z); d[3] = f2bf(v.w);
    }
    __syncthreads();
    unsigned short* dst = xT + ((size_t)b * HW + (size_t)y * W_) * 64;
    #pragma unroll
    for (int i = 0; i < 4; ++i) {
        const int o    = (t + i * 256) * 8;
        const int xcol = o >> 6;
        const int c0   = o & 63;
        union { bf16x8 v; unsigned short u[8]; } pk;
        #pragma unroll
        for (int j = 0; j < 8; ++j) pk.u[j] = ld[(c0 + j) * 132 + xcol];
        *(bf16x8*)(dst + o) = pk.v;
    }
}

__global__ void prep_weight_fb(const float* __restrict__ w,
                               unsigned short* __restrict__ wt)
{
    const int i = blockIdx.x * 256 + threadIdx.x;
    if (i >= 9 * 64 * 64) return;
    const int k  = i >> 12;
    const int r  = i & 4095;
    const int co = r >> 6;
    const int c  = r & 63;
    wt[i] = f2bf(w[co * KPOS + c * 9 + k]);
}

__global__ __launch_bounds__(256, 4)
void dcn_mfma_nhwc(const unsigned short* __restrict__ xT,
                   const float* __restrict__ offset,
                   const float* __restrict__ mask,
                   const float* __restrict__ bias,
                   const unsigned short* __restrict__ wprep,
                   float* __restrict__ out)
{
    __shared__ unsigned short vP[2][64][72];
    __shared__ unsigned short Wk[2][64][72];
    const int t   = threadIdx.x;
    const int bid = blockIdx.x;
    const int wk  = ((bid & 7) << 7) | (bid >> 3);
    const int xh  = wk & 1;
    const int ho  = (wk >> 1) & 127;
    const int b   = wk >> 8;
    const int cq  = t >> 6;
    const int lane = t & 63;
    const int px_sub = lane >> 4;
    const int c4     = lane & 15;
    f32x4 acc[4];
    #pragma unroll
    for (int i = 0; i < 4; ++i) acc[i] = (f32x4){0.f, 0.f, 0.f, 0.f};
    const unsigned short* xTb = xT + (size_t)b * HW * 64;

    auto stage = [&](int k, int s) {
        int   idxs[4][4];
        float wts [4][4];
        #pragma unroll
        for (int it = 0; it < 4; ++it) {
            const int pl = (cq << 4) | (it << 2) | px_sub;
            const int wo = xh * 64 + pl;
            const int obase = ((b * 18 + 2 * k) * H_ + ho) * W_ + wo;
            const float dy = offset[obase];
            const float dx = offset[obase + HW];
            const float mm = mask[((b * 9 + k) * H_ + ho) * W_ + wo];
            const float py  = dy + (float)(k / 3) + (float)(ho - 1);
            const float pxx = dx + (float)(k % 3) + (float)(wo - 1);
            const float y0f = floorf(py), x0f = floorf(pxx);
            const float wy = py - y0f, wx = pxx - x0f;
            const int y0 = (int)y0f, x0 = (int)x0f;
            const int y1 = y0 + 1,  x1 = x0 + 1;
            const bool vy0 = (y0 >= 0) & (y0 < H_), vy1 = (y1 >= 0) & (y1 < H_);
            const bool vx0 = (x0 >= 0) & (x0 < W_), vx1 = (x1 >= 0) & (x1 < W_);
            const int cy0 = min(max(y0, 0), H_-1), cy1 = min(max(y1, 0), H_-1);
            const int cx0 = min(max(x0, 0), W_-1), cx1 = min(max(x1, 0), W_-1);
            idxs[it][0] = (cy0 * W_ + cx0) << 6;
            idxs[it][1] = (cy0 * W_ + cx1) << 6;
            idxs[it][2] = (cy1 * W_ + cx0) << 6;
            idxs[it][3] = (cy1 * W_ + cx1) << 6;
            wts[it][0] = (vy0 && vx0) ? (1.f - wy) * (1.f - wx) * mm : 0.f;
            wts[it][1] = (vy0 && vx1) ? (1.f - wy) * wx * mm         : 0.f;
            wts[it][2] = (vy1 && vx0) ? wy * (1.f - wx) * mm         : 0.f;
            wts[it][3] = (vy1 && vx1) ? wy * wx * mm                 : 0.f;
        }
        bf16x4 cr[4][4];
        #pragma unroll
        for (int it = 0; it < 4; ++it)
            #pragma unroll
            for (int cn = 0; cn < 4; ++cn)
                cr[it][cn] = *(const bf16x4*)(xTb + idxs[it][cn] + (c4 << 2));
        #pragma unroll
        for (int q = 0; q < 2; ++q) {
            const int j  = q * 2048 + t * 8;
            *(bf16x8*)&Wk[s][j >> 6][j & 63] = *(const bf16x8*)(wprep + k * 4096 + j);
        }
        #pragma unroll
        for (int it = 0; it < 4; ++it) {
            const int pl = (cq << 4) | (it << 2) | px_sub;
            union { bf16x4 v; unsigned short u[4]; } pk;
            #pragma unroll
            for (int j = 0; j < 4; ++j) {
                union { short s; unsigned short u; } s0{cr[it][0][j]}, s1{cr[it][1][j]},
                                                     s2{cr[it][2][j]}, s3{cr[it][3][j]};
                const float v = wts[it][0] * bfl(s0.u) + wts[it][1] * bfl(s1.u)
                              + wts[it][2] * bfl(s2.u) + wts[it][3] * bfl(s3.u);
                pk.u[j] = f2bf(v);
            }
            *(bf16x4*)&vP[s][pl][c4 << 2] = pk.v;
        }
    };
    auto domfma = [&](int s) {
        const int ra = cq * 16 + (lane & 15);
        const int kc = (lane >> 4) * 8;
        #pragma unroll
        for (int ks = 0; ks < 2; ++ks) {
            const int kcol = ks * 32 + kc;
            const bf16x8 a = *(const bf16x8*)&vP[s][ra][kcol];
            #pragma unroll
            for (int nt = 0; nt < 4; ++nt) {
                const bf16x8 bb = *(const bf16x8*)&Wk[s][nt * 16 + (lane & 15)][kcol];
                acc[nt] = __builtin_amdgcn_mfma_f32_16x16x32_bf16(a, bb, acc[nt], 0, 0, 0);
            }
        }
    };
    stage(0, 0);
    __syncthreads();
    for (int k = 0; k < 9; ++k) {
        const int s = k & 1;
        if (k < 8) stage(k + 1, s ^ 1);
        domfma(s);
        __syncthreads();
    }
    const int px0 = cq * 16 + (lane >> 4) * 4;
    #pragma unroll
    for (int nt = 0; nt < 4; ++nt) {
        const int co = nt * 16 + (lane & 15);
        const float bb = bias[co];
        float4 r;
        r.x = acc[nt][0] + bb;
        r.y = acc[nt][1] + bb;
        r.z = acc[nt][2] + bb;
        r.w = acc[nt][3] + bb;
        *(float4*)&out[(((size_t)b * COUT_ + co) * H_ + ho) * W_ + xh * 64 + px0] = r;
    }
}

extern "C" void kernel_launch(void* const* d_in, const int* in_sizes, int n_in,
                              void* d_out, int out_size, void* d_ws, size_t ws_size,
                              hipStream_t stream)
{
    const float* x      = (const float*)d_in[0];
    const float* offset = (const float*)d_in[1];
    const float* mask   = (const float*)d_in[2];
    const float* weight = (const float*)d_in[3];
    const float* bias   = (const float*)d_in[4];
    float* out = (float*)d_out;

    dim3 block(256);
    dim3 grid(B_ * H_ * 2);

    if (ws_size >= WS_NEED3) {
        _Float16* xT    = (_Float16*)d_ws;
        _Float16* wprep = xT + XT_HALFS;
        unsigned* mOffs = (unsigned*)((char*)d_ws + OFFS_BYTE);
        f16x4*    mWts  = (f16x4*)  ((char*)d_ws + WTS_BYTE);
        prep_all<<<dim3(2960), block, 0, stream>>>(x, offset, mask, weight,
                                                   xT, wprep, mOffs, mWts);
        dcn_f16<<<grid, block, 0, stream>>>(xT, mOffs, mWts, bias, wprep, out);
    } else {
        unsigned short* xTb   = (unsigned short*)d_ws;
        unsigned short* wprep = xTb + XT_HALFS;
        xpose_bf16<<<dim3(B_ * H_), block, 0, stream>>>(x, xTb);
        prep_weight_fb<<<dim3(144), block, 0, stream>>>(weight, wprep);
        dcn_mfma_nhwc<<<grid, block, 0, stream>>>(xTb, offset, mask, bias, wprep, out);
    }
}

// Round 14
// 34.813 us; speedup vs baseline: 1.5476x; 1.5476x over previous
//
#include <hip/hip_runtime.h>

#define B_    4
#define CIN_  64
#define H_    128
#define W_    128
#define COUT_ 64
#define HW    (H_*W_)
#define KPOS  576

typedef __attribute__((ext_vector_type(8))) short    bf16x8;
typedef __attribute__((ext_vector_type(4))) short    bf16x4;
typedef __attribute__((ext_vector_type(4))) float    f32x4;
typedef __attribute__((ext_vector_type(4))) _Float16 f16x4;
typedef __attribute__((ext_vector_type(8))) _Float16 f16x8;

static __device__ __forceinline__ unsigned short f2bf(float f) {
    union { float f; unsigned u; } a; a.f = f;
    unsigned r = a.u + 0x7fffu + ((a.u >> 16) & 1u);   // RNE
    return (unsigned short)(r >> 16);
}
static __device__ __forceinline__ float bfl(unsigned u) {
    union { unsigned x; float f; } a; a.x = u << 16; return a.f;
}

// Barrier that waits ONLY on LDS ops (lgkmcnt), never vmcnt: prefetched
// global loads stay in flight across taps (T4: counted waits, no drain-0).
static __device__ __forceinline__ void softbar() {
    asm volatile("s_waitcnt lgkmcnt(0)\n\ts_barrier" ::: "memory");
}

#define XT_HALFS   4194304                       // B*HW*64 NHWC f16 image
#define WP_HALFS   36864                         // wt[k][co][c] f16
#define META_CNT   (B_*9*HW)                     // 589824
#define OFFS_BYTE  ((XT_HALFS + WP_HALFS) * 2)            // 8462336
#define WTS_BYTE   (OFFS_BYTE + META_CNT * 4)             // 10821632
#define WS_NEED3   ((size_t)(WTS_BYTE + META_CNT * 8))    // ~15.5 MB

// ================= fused prep: xpose | meta | weight (all f16) =============
__global__ __launch_bounds__(256)
void prep_all(const float* __restrict__ x,
              const float* __restrict__ offset,
              const float* __restrict__ mask,
              const float* __restrict__ w,
              _Float16* __restrict__ xT,
              _Float16* __restrict__ wt,
              unsigned* __restrict__ mOffs,
              f16x4* __restrict__ mWts)
{
    const int bid = blockIdx.x;
    const int t   = threadIdx.x;

    if (bid < 512) {
        // ---- x NCHW f32 -> NHWC f16 (one (b,y) row per block) ----
        __shared__ _Float16 ld[64 * 132];
        const int b = bid >> 7;
        const int y = bid & 127;
        const float* src = x + (size_t)b * 64 * HW + y * W_;
        #pragma unroll
        for (int i = 0; i < 8; ++i) {
            const int e4 = (t + i * 256) * 4;
            const int c  = e4 >> 7;
            const int x0 = e4 & 127;
            const float4 v = *(const float4*)(src + (size_t)c * HW + x0);
            _Float16* d = &ld[c * 132 + x0];
            d[0] = (_Float16)v.x; d[1] = (_Float16)v.y;
            d[2] = (_Float16)v.z; d[3] = (_Float16)v.w;
        }
        __syncthreads();
        _Float16* dst = xT + ((size_t)b * HW + (size_t)y * W_) * 64;
        #pragma unroll
        for (int i = 0; i < 4; ++i) {
            const int o    = (t + i * 256) * 8;
            const int xcol = o >> 6;
            const int c0   = o & 63;
            union { f16x8 v; _Float16 u[8]; } pk;
            #pragma unroll
            for (int j = 0; j < 8; ++j) pk.u[j] = ld[(c0 + j) * 132 + xcol];
            *(f16x8*)(dst + o) = pk.v;
        }
    } else if (bid < 2816) {
        // ---- sampling metadata per (b,tap,pixel) ----
        const int i  = (bid - 512) * 256 + t;
        const int gp = i & (HW - 1);
        const int bk = i >> 14;              // b*9 + k
        const int b  = bk / 9;
        const int k  = bk - b * 9;
        const int ho = gp >> 7, wo = gp & 127;
        const float dy = offset[(size_t)(b * 18 + 2 * k) * HW + gp];
        const float dx = offset[(size_t)(b * 18 + 2 * k + 1) * HW + gp];
        const float mm = mask[(size_t)bk * HW + gp];
        const float py  = dy + (float)(k / 3) + (float)(ho - 1);   // PAD=1
        const float pxx = dx + (float)(k % 3) + (float)(wo - 1);
        const float y0f = floorf(py), x0f = floorf(pxx);
        const float wy = py - y0f, wx = pxx - x0f;
        const int y0 = (int)y0f, x0 = (int)x0f;
        const int y1 = y0 + 1,  x1 = x0 + 1;
        const bool vy0 = (y0 >= 0) & (y0 < H_), vy1 = (y1 >= 0) & (y1 < H_);
        const bool vx0 = (x0 >= 0) & (x0 < W_), vx1 = (x1 >= 0) & (x1 < W_);
        const int cy0 = min(max(y0, 0), H_-1), cy1 = min(max(y1, 0), H_-1);
        const int cx0 = min(max(x0, 0), W_-1), cx1 = min(max(x1, 0), W_-1);
        mOffs[i] = (unsigned)cy0 | ((unsigned)cy1 << 8)
                 | ((unsigned)cx0 << 16) | ((unsigned)cx1 << 24);
        f16x4 wv;
        wv[0] = (_Float16)((vy0 && vx0) ? (1.f - wy) * (1.f - wx) * mm : 0.f);
        wv[1] = (_Float16)((vy0 && vx1) ? (1.f - wy) * wx * mm         : 0.f);
        wv[2] = (_Float16)((vy1 && vx0) ? wy * (1.f - wx) * mm         : 0.f);
        wv[3] = (_Float16)((vy1 && vx1) ? wy * wx * mm                 : 0.f);
        mWts[i] = wv;
    } else {
        // ---- weight -> f16, tap-major: wt[k][co][c] ----
        const int i = (bid - 2816) * 256 + t;
        if (i < 9 * 64 * 64) {
            const int k  = i >> 12;
            const int r  = i & 4095;
            const int co = r >> 6;
            const int c  = r & 63;
            wt[i] = (_Float16)w[co * KPOS + c * 9 + k];
        }
    }
}

// ================= main: R12 champion — LDS-paced f16 pipeline ============
// Per iter k: wkload(k+1)->regs | metald(k+2) | domfma(k) | gather(k+2) |
// finish(k+1) {Wk LDS write + combine + vP write} | softbar.
// The vP LDS round-trip is load-bearing: it decouples gather latency from
// MFMA consumption (register-direct variants R6-R9/R13 all regressed —
// compiler sinks the gather loads to uses, VGPR collapses to ~60).
__global__ __launch_bounds__(256, 4)
void dcn_f16(const _Float16* __restrict__ xT,
             const unsigned* __restrict__ mOffs,
             const f16x4* __restrict__ mWts,
             const float* __restrict__ bias,
             const _Float16* __restrict__ wprep,
             float* __restrict__ out)
{
    __shared__ _Float16 vP[2][64][72];
    __shared__ _Float16 Wk[2][64][72];

    const int t   = threadIdx.x;
    const int bid = blockIdx.x;
    const int wk  = ((bid & 7) << 7) | (bid >> 3);   // XCD-chunked swizzle
    const int xh  = wk & 1;
    const int ho  = (wk >> 1) & 127;
    const int b   = wk >> 8;
    const int cq  = t >> 6;
    const int lane = t & 63;
    const int pxl  = lane >> 2;          // 0..15 pixel within wave tile
    const int coct = lane & 3;           // 0..3 channel oct

    f32x4 acc[4];
    #pragma unroll
    for (int i = 0; i < 4; ++i) acc[i] = (f32x4){0.f, 0.f, 0.f, 0.f};

    const _Float16* xTb = xT + (size_t)b * HW * 64;
    const int gp    = ho * W_ + xh * 64 + cq * 16 + pxl;
    const int mbase = (b * 9) << 14;

    // rolling pipeline state (static indices under full unroll)
    unsigned mO[2]; f16x4 mW[2];
    f16x8 cr[2][2][4];                   // [tap parity][pass][corner]
    f16x8 wa0, wa1;                      // W-stage registers (T14 split)

    auto metald = [&](int k, int s) {
        const int mi = mbase + (k << 14) + gp;
        mO[s] = mOffs[mi];
        mW[s] = mWts[mi];
    };
    auto gather = [&](int k, int s) {
        const unsigned pk = mO[s];
        const int y0c = pk & 255,         y1c = (pk >> 8) & 255;
        const int x0c = (pk >> 16) & 255, x1c = (int)(pk >> 24);
        const int cho = coct * 8;
        const int p00 = (((y0c << 7) | x0c) << 6) + cho;
        const int p01 = (((y0c << 7) | x1c) << 6) + cho;
        const int p10 = (((y1c << 7) | x0c) << 6) + cho;
        const int p11 = (((y1c << 7) | x1c) << 6) + cho;
        #pragma unroll
        for (int pass = 0; pass < 2; ++pass) {
            const int o = pass * 32;
            cr[s][pass][0] = *(const f16x8*)(xTb + p00 + o);
            cr[s][pass][1] = *(const f16x8*)(xTb + p01 + o);
            cr[s][pass][2] = *(const f16x8*)(xTb + p10 + o);
            cr[s][pass][3] = *(const f16x8*)(xTb + p11 + o);
        }
    };
    auto wkload = [&](int k) {
        const int j = t * 8;
        wa0 = *(const f16x8*)(wprep + k * 4096 + j);
        wa1 = *(const f16x8*)(wprep + k * 4096 + 2048 + j);
    };
    auto finish = [&](int k, int s) {
        // write staged W regs to LDS
        const int j  = t * 8;
        *(f16x8*)&Wk[s][j >> 6][j & 63] = wa0;
        const int j2 = 2048 + j;
        *(f16x8*)&Wk[s][j2 >> 6][j2 & 63] = wa1;
        // packed-f16 bilinear combine -> A-fragment slice, write vP
        const _Float16 w0 = mW[s][0];
        const _Float16 w1 = mW[s][1];
        const _Float16 w2 = mW[s][2];
        const _Float16 w3 = mW[s][3];
        #pragma unroll
        for (int pass = 0; pass < 2; ++pass) {
            f16x8 a = cr[s][pass][0] * w0 + cr[s][pass][1] * w1
                    + cr[s][pass][2] * w2 + cr[s][pass][3] * w3;
            *(f16x8*)&vP[s][cq * 16 + pxl][pass * 32 + coct * 8] = a;
        }
    };
    auto domfma = [&](int k) {
        const int s  = k & 1;
        const int ra = cq * 16 + (lane & 15);
        const int kc = (lane >> 4) * 8;
        #pragma unroll
        for (int ks = 0; ks < 2; ++ks) {
            const int kcol = ks * 32 + kc;
            const f16x8 a = *(const f16x8*)&vP[s][ra][kcol];
            #pragma unroll
            for (int nt = 0; nt < 4; ++nt) {
                const f16x8 bb = *(const f16x8*)&Wk[s][nt * 16 + (lane & 15)][kcol];
                acc[nt] = __builtin_amdgcn_mfma_f32_16x16x32_f16(a, bb, acc[nt], 0, 0, 0);
            }
        }
    };

    // ---- prologue: taps 0 and 1 in flight, tap 0 finished ----
    metald(0, 0);
    metald(1, 1);
    gather(0, 0);
    gather(1, 1);
    wkload(0);
    finish(0, 0);
    softbar();

    #pragma unroll
    for (int k = 0; k < 9; ++k) {
        const int s = k & 1;
        if (k < 8) wkload(k + 1);        // next tap's W into regs (L1-hot)
        if (k < 7) metald(k + 2, s);     // meta 2 ahead (slot s free now)
        domfma(k);                       // compute; covers meta/W latency
        if (k < 7) gather(k + 2, s);     // gathers issued 2 taps ahead
        if (k < 8) {
            finish(k + 1, s ^ 1);        // wait cr[(k+1)&1] (1.5 iters old)
            softbar();                   // lgkm-only: gathers stay in flight
        }
    }

    // ---- epilogue: D col = lane&15 (co), row = (lane>>4)*4+j (pixel) ----
    const int px0 = cq * 16 + (lane >> 4) * 4;
    #pragma unroll
    for (int nt = 0; nt < 4; ++nt) {
        const int co = nt * 16 + (lane & 15);
        const float bb = bias[co];
        float4 r;
        r.x = acc[nt][0] + bb;
        r.y = acc[nt][1] + bb;
        r.z = acc[nt][2] + bb;
        r.w = acc[nt][3] + bb;
        *(float4*)&out[(((size_t)b * COUT_ + co) * H_ + ho) * W_ + xh * 64 + px0] = r;
    }
}

// ================= fallback path (ws too small): R4 bf16 kernels ===========
__global__ __launch_bounds__(256)
void xpose_bf16(const float* __restrict__ x, unsigned short* __restrict__ xT)
{
    __shared__ unsigned short ld[64 * 132];
    const int t   = threadIdx.x;
    const int blk = blockIdx.x;
    const int b   = blk >> 7;
    const int y   = blk & 127;
    const float* src = x + (size_t)b * 64 * HW + y * W_;
    #pragma unroll
    for (int i = 0; i < 8; ++i) {
        const int e4 = (t + i * 256) * 4;
        const int c  = e4 >> 7;
        const int x0 = e4 & 127;
        const float4 v = *(const float4*)(src + (size_t)c * HW + x0);
        unsigned short* d = &ld[c * 132 + x0];
        d[0] = f2bf(v.x); d[1] = f2bf(v.y); d[2] = f2bf(v.z); d[3] = f2bf(v.w);
    }
    __syncthreads();
    unsigned short* dst = xT + ((size_t)b * HW + (size_t)y * W_) * 64;
    #pragma unroll
    for (int i = 0; i < 4; ++i) {
        const int o    = (t + i * 256) * 8;
        const int xcol = o >> 6;
        const int c0   = o & 63;
        union { bf16x8 v; unsigned short u[8]; } pk;
        #pragma unroll
        for (int j = 0; j < 8; ++j) pk.u[j] = ld[(c0 + j) * 132 + xcol];
        *(bf16x8*)(dst + o) = pk.v;
    }
}

__global__ void prep_weight_fb(const float* __restrict__ w,
                               unsigned short* __restrict__ wt)
{
    const int i = blockIdx.x * 256 + threadIdx.x;
    if (i >= 9 * 64 * 64) return;
    const int k  = i >> 12;
    const int r  = i & 4095;
    const int co = r >> 6;
    const int c  = r & 63;
    wt[i] = f2bf(w[co * KPOS + c * 9 + k]);
}

__global__ __launch_bounds__(256, 4)
void dcn_mfma_nhwc(const unsigned short* __restrict__ xT,
                   const float* __restrict__ offset,
                   const float* __restrict__ mask,
                   const float* __restrict__ bias,
                   const unsigned short* __restrict__ wprep,
                   float* __restrict__ out)
{
    __shared__ unsigned short vP[2][64][72];
    __shared__ unsigned short Wk[2][64][72];
    const int t   = threadIdx.x;
    const int bid = blockIdx.x;
    const int wk  = ((bid & 7) << 7) | (bid >> 3);
    const int xh  = wk & 1;
    const int ho  = (wk >> 1) & 127;
    const int b   = wk >> 8;
    const int cq  = t >> 6;
    const int lane = t & 63;
    const int px_sub = lane >> 4;
    const int c4     = lane & 15;
    f32x4 acc[4];
    #pragma unroll
    for (int i = 0; i < 4; ++i) acc[i] = (f32x4){0.f, 0.f, 0.f, 0.f};
    const unsigned short* xTb = xT + (size_t)b * HW * 64;

    auto stage = [&](int k, int s) {
        int   idxs[4][4];
        float wts [4][4];
        #pragma unroll
        for (int it = 0; it < 4; ++it) {
            const int pl = (cq << 4) | (it << 2) | px_sub;
            const int wo = xh * 64 + pl;
            const int obase = ((b * 18 + 2 * k) * H_ + ho) * W_ + wo;
            const float dy = offset[obase];
            const float dx = offset[obase + HW];
            const float mm = mask[((b * 9 + k) * H_ + ho) * W_ + wo];
            const float py  = dy + (float)(k / 3) + (float)(ho - 1);
            const float pxx = dx + (float)(k % 3) + (float)(wo - 1);
            const float y0f = floorf(py), x0f = floorf(pxx);
            const float wy = py - y0f, wx = pxx - x0f;
            const int y0 = (int)y0f, x0 = (int)x0f;
            const int y1 = y0 + 1,  x1 = x0 + 1;
            const bool vy0 = (y0 >= 0) & (y0 < H_), vy1 = (y1 >= 0) & (y1 < H_);
            const bool vx0 = (x0 >= 0) & (x0 < W_), vx1 = (x1 >= 0) & (x1 < W_);
            const int cy0 = min(max(y0, 0), H_-1), cy1 = min(max(y1, 0), H_-1);
            const int cx0 = min(max(x0, 0), W_-1), cx1 = min(max(x1, 0), W_-1);
            idxs[it][0] = (cy0 * W_ + cx0) << 6;
            idxs[it][1] = (cy0 * W_ + cx1) << 6;
            idxs[it][2] = (cy1 * W_ + cx0) << 6;
            idxs[it][3] = (cy1 * W_ + cx1) << 6;
            wts[it][0] = (vy0 && vx0) ? (1.f - wy) * (1.f - wx) * mm : 0.f;
            wts[it][1] = (vy0 && vx1) ? (1.f - wy) * wx * mm         : 0.f;
            wts[it][2] = (vy1 && vx0) ? wy * (1.f - wx) * mm         : 0.f;
            wts[it][3] = (vy1 && vx1) ? wy * wx * mm                 : 0.f;
        }
        bf16x4 cr[4][4];
        #pragma unroll
        for (int it = 0; it < 4; ++it)
            #pragma unroll
            for (int cn = 0; cn < 4; ++cn)
                cr[it][cn] = *(const bf16x4*)(xTb + idxs[it][cn] + (c4 << 2));
        #pragma unroll
        for (int q = 0; q < 2; ++q) {
            const int j  = q * 2048 + t * 8;
            *(bf16x8*)&Wk[s][j >> 6][j & 63] = *(const bf16x8*)(wprep + k * 4096 + j);
        }
        #pragma unroll
        for (int it = 0; it < 4; ++it) {
            const int pl = (cq << 4) | (it << 2) | px_sub;
            union { bf16x4 v; unsigned short u[4]; } pk;
            #pragma unroll
            for (int j = 0; j < 4; ++j) {
                union { short s; unsigned short u; } s0{cr[it][0][j]}, s1{cr[it][1][j]},
                                                     s2{cr[it][2][j]}, s3{cr[it][3][j]};
                const float v = wts[it][0] * bfl(s0.u) + wts[it][1] * bfl(s1.u)
                              + wts[it][2] * bfl(s2.u) + wts[it][3] * bfl(s3.u);
                pk.u[j] = f2bf(v);
            }
            *(bf16x4*)&vP[s][pl][c4 << 2] = pk.v;
        }
    };
    auto domfma = [&](int s) {
        const int ra = cq * 16 + (lane & 15);
        const int kc = (lane >> 4) * 8;
        #pragma unroll
        for (int ks = 0; ks < 2; ++ks) {
            const int kcol = ks * 32 + kc;
            const bf16x8 a = *(const bf16x8*)&vP[s][ra][kcol];
            #pragma unroll
            for (int nt = 0; nt < 4; ++nt) {
                const bf16x8 bb = *(const bf16x8*)&Wk[s][nt * 16 + (lane & 15)][kcol];
                acc[nt] = __builtin_amdgcn_mfma_f32_16x16x32_bf16(a, bb, acc[nt], 0, 0, 0);
            }
        }
    };
    stage(0, 0);
    __syncthreads();
    for (int k = 0; k < 9; ++k) {
        const int s = k & 1;
        if (k < 8) stage(k + 1, s ^ 1);
        domfma(s);
        __syncthreads();
    }
    const int px0 = cq * 16 + (lane >> 4) * 4;
    #pragma unroll
    for (int nt = 0; nt < 4; ++nt) {
        const int co = nt * 16 + (lane & 15);
        const float bb = bias[co];
        float4 r;
        r.x = acc[nt][0] + bb;
        r.y = acc[nt][1] + bb;
        r.z = acc[nt][2] + bb;
        r.w = acc[nt][3] + bb;
        *(float4*)&out[(((size_t)b * COUT_ + co) * H_ + ho) * W_ + xh * 64 + px0] = r;
    }
}

extern "C" void kernel_launch(void* const* d_in, const int* in_sizes, int n_in,
                              void* d_out, int out_size, void* d_ws, size_t ws_size,
                              hipStream_t stream)
{
    const float* x      = (const float*)d_in[0];
    const float* offset = (const float*)d_in[1];
    const float* mask   = (const float*)d_in[2];
    const float* weight = (const float*)d_in[3];
    const float* bias   = (const float*)d_in[4];
    float* out = (float*)d_out;

    dim3 block(256);
    dim3 grid(B_ * H_ * 2);

    if (ws_size >= WS_NEED3) {
        _Float16* xT    = (_Float16*)d_ws;
        _Float16* wprep = xT + XT_HALFS;
        unsigned* mOffs = (unsigned*)((char*)d_ws + OFFS_BYTE);
        f16x4*    mWts  = (f16x4*)  ((char*)d_ws + WTS_BYTE);
        prep_all<<<dim3(2960), block, 0, stream>>>(x, offset, mask, weight,
                                                   xT, wprep, mOffs, mWts);
        dcn_f16<<<grid, block, 0, stream>>>(xT, mOffs, mWts, bias, wprep, out);
    } else {
        unsigned short* xTb   = (unsigned short*)d_ws;
        unsigned short* wprep = xTb + XT_HALFS;
        xpose_bf16<<<dim3(B_ * H_), block, 0, stream>>>(x, xTb);
        prep_weight_fb<<<dim3(144), block, 0, stream>>>(weight, wprep);
        dcn_mfma_nhwc<<<grid, block, 0, stream>>>(xTb, offset, mask, bias, wprep, out);
    }
}